// Round 1
// baseline (9459.274 us; speedup 1.0000x reference)
//
#include <hip/hip_runtime.h>

#define T_LEN 512
#define BATCH 32
#define HSZ 512
#define G3 1536
#define MROWS 16384  // T_LEN * BATCH

typedef unsigned int u32;
typedef unsigned long long u64;
typedef unsigned short u16;
typedef __attribute__((ext_vector_type(8))) short bf16x8;
typedef __attribute__((ext_vector_type(4))) float f32x4;

// ---------- helpers ----------
static __device__ __forceinline__ u16 f2bf(float x) {
  u32 u = __float_as_uint(x);
  u32 r = (u + 0x7FFFu + ((u >> 16) & 1u)) >> 16;
  return (u16)r;
}
static __device__ __forceinline__ u32 pack_bf16(float a, float b) {
  return (u32)f2bf(a) | ((u32)f2bf(b) << 16);
}
static __device__ __forceinline__ float nz(float x) { return (x == x) ? x : 0.f; }

// ---------- conversion kernels ----------
__global__ __launch_bounds__(256) void transpose_bf16(
    const float* __restrict__ src, u16* __restrict__ dst, int K, int N)
{
  int dirz = blockIdx.z;
  src += (size_t)dirz * K * N;
  dst += (size_t)dirz * N * K;
  __shared__ float tile[32][33];
  int n0 = blockIdx.x * 32, k0 = blockIdx.y * 32;
  int tx = threadIdx.x & 31, ty = threadIdx.x >> 5;
#pragma unroll
  for (int i = ty; i < 32; i += 8)
    tile[i][tx] = src[(size_t)(k0 + i) * N + n0 + tx];
  __syncthreads();
#pragma unroll
  for (int i = ty; i < 32; i += 8)
    dst[(size_t)(n0 + i) * K + k0 + tx] = f2bf(tile[tx][i]);
}

__global__ __launch_bounds__(256) void convert_x(
    const float* __restrict__ src, u16* __restrict__ dst, int n4)
{
  int i = blockIdx.x * 256 + threadIdx.x;
  if (i >= n4) return;
  float4 v = ((const float4*)src)[i];
  union { u16 h[4]; uint2 u; } o;
  o.h[0] = f2bf(v.x); o.h[1] = f2bf(v.y); o.h[2] = f2bf(v.z); o.h[3] = f2bf(v.w);
  ((uint2*)dst)[i] = o.u;
}

// ---------- input-gate GEMM ----------
// C is now TRANSPOSED: [2][N=G3][M] fp16, so the recurrent kernel reads
// batch-contiguous 8B chunks and the epilogue stores 8B vectors.
__global__ __launch_bounds__(256) void gemm_gi(
    const u16* __restrict__ A,   // [M][K] bf16
    const u16* __restrict__ Bw,  // [2][N][K] bf16
    const float* __restrict__ bias,
    _Float16* __restrict__ C,    // [2][N][M]  (transposed!)
    int M, int K)
{
  const int N = G3;
  int dir = blockIdx.z;
  const u16* Bd = Bw + (size_t)dir * N * K;
  _Float16* Cd = C + (size_t)dir * N * M;
  const float* biasd = bias + dir * N;

  int tm = blockIdx.x * 128;
  int tn = blockIdx.y * 128;

  __shared__ u16 sA[128][40];
  __shared__ u16 sB[128][40];

  int tid = threadIdx.x;
  int lane = tid & 63, wave = tid >> 6;
  int wm = (wave & 1) << 6, wn = (wave >> 1) << 6;

  f32x4 acc[4][4] = {};

  int srow = tid >> 1, shalf = (tid & 1) << 4;
  const u16* pa = A + (size_t)(tm + srow) * K + shalf;
  const u16* pb = Bd + (size_t)(tn + srow) * K + shalf;

  for (int k0 = 0; k0 < K; k0 += 32) {
    uint4 va0 = *(const uint4*)(pa + k0);
    uint4 va1 = *(const uint4*)(pa + k0 + 8);
    uint4 vb0 = *(const uint4*)(pb + k0);
    uint4 vb1 = *(const uint4*)(pb + k0 + 8);
    *(uint4*)&sA[srow][shalf]     = va0;
    *(uint4*)&sA[srow][shalf + 8] = va1;
    *(uint4*)&sB[srow][shalf]     = vb0;
    *(uint4*)&sB[srow][shalf + 8] = vb1;
    __syncthreads();
    int kg = (lane >> 4) << 3;
    int r16 = lane & 15;
    bf16x8 af[4], bfr[4];
#pragma unroll
    for (int f = 0; f < 4; f++) {
      af[f]  = *(const bf16x8*)&sA[wm + f * 16 + r16][kg];
      bfr[f] = *(const bf16x8*)&sB[wn + f * 16 + r16][kg];
    }
#pragma unroll
    for (int fm = 0; fm < 4; fm++)
#pragma unroll
      for (int fn = 0; fn < 4; fn++)
        acc[fm][fn] = __builtin_amdgcn_mfma_f32_16x16x32_bf16(af[fm], bfr[fn], acc[fm][fn], 0, 0, 0);
    __syncthreads();
  }

  // epilogue: C^T store, 4 consecutive rows per lane -> one 8B store
  int col4 = lane & 15, rbase = (lane >> 4) << 2;
#pragma unroll
  for (int fn = 0; fn < 4; fn++) {
    int col = tn + wn + fn * 16 + col4;
    float bv = biasd[col];
#pragma unroll
    for (int fm = 0; fm < 4; fm++) {
      int row0 = tm + wm + fm * 16 + rbase;
      union { _Float16 h[4]; uint2 u; } o;
#pragma unroll
      for (int r = 0; r < 4; r++)
        o.h[r] = (_Float16)nz(acc[fm][fn][r] + bv);
      *(uint2*)&Cd[(size_t)col * M + row0] = o.u;
    }
  }
}

// ---------- persistent recurrent kernel ----------
// 64 blocks x 64 threads (1 wave). block=(dir,jc): 16 j-cols, 32 batches, 3 gates.
// Changes vs prior version:
//   * W_hh fragments live in 192 VGPRs (no LDS, no ds_read on the step path)
//   * gi is [dir][G3][M]: 6 x 8B vector loads per step (dense lines)
//   * out stores are regular (NT stores ack at HBM and stall the next poll
//     via the shared vmcnt counter; regular stores ack at L2)
//   * gate math uses v_rcp instead of full-precision divides
__global__ __launch_bounds__(64, 1) void gru_rec(
    const _Float16* __restrict__ gi,   // [2][G3][MROWS] fp16 (transposed)
    const u16* __restrict__ whhT,      // [2][G3][HSZ] bf16
    const float* __restrict__ bhh,     // [2][G3]
    const float* __restrict__ h0,      // [2][B][HSZ]
    float* __restrict__ outF,          // [T][B][1024] or null
    u16* __restrict__ outB,            // [T][B][1024] bf16 or null
    u32* __restrict__ hbuf,            // [2 buf][2 dir][B][HSZ/2] packed bf16
    int* __restrict__ flags,           // [2][32] x 64B-padded lines
    int base)                          // layer * 513
{
  int dir = blockIdx.x >> 5;
  int jc  = blockIdx.x & 31;
  int lane = threadIdx.x;          // one wave
  int l15 = lane & 15;
  int q   = lane >> 4;             // 0..3
  int j   = jc * 16 + l15;         // output column
  int kq  = q * 8;                 // k offset within 32-k step

  // ---- W_hh fragments into registers (constant across all 512 steps) ----
  bf16x8 wf[3][16];
  {
    const u16* wb = whhT + ((size_t)dir * G3 + j) * HSZ + kq;
#pragma unroll
    for (int g = 0; g < 3; g++)
#pragma unroll
      for (int kg = 0; kg < 16; kg++)
        wf[g][kg] = *(const bf16x8*)(wb + ((size_t)g * 512) * HSZ + kg * 32);
  }

  float bhr = bhh[dir * G3 + j];
  float bhz = bhh[dir * G3 + 512 + j];
  float bhn = bhh[dir * G3 + 1024 + j];

  float hm[8];
#pragma unroll
  for (int mt = 0; mt < 2; mt++)
#pragma unroll
    for (int r = 0; r < 4; r++)
      hm[mt * 4 + r] = h0[((size_t)dir * BATCH + mt * 16 + q * 4 + r) * HSZ + j];

  // publish h0 into buffer 0 (write-through atomics, packed pairs)
  {
    u32* hb = hbuf + (size_t)dir * (BATCH * HSZ / 2);
#pragma unroll
    for (int i = 0; i < 8; i++) {
      int b = (i >> 2) * 16 + q * 4 + (i & 3);
      float partner = __shfl_xor(hm[i], 1);
      if (!(l15 & 1))
        __hip_atomic_store(&hb[(size_t)b * (HSZ / 2) + (j >> 1)], pack_bf16(hm[i], partner),
                           __ATOMIC_RELAXED, __HIP_MEMORY_SCOPE_AGENT);
    }
  }
  __builtin_amdgcn_fence(__ATOMIC_RELEASE, "workgroup");
  __builtin_amdgcn_s_waitcnt(0);
  if (lane == 0)
    __hip_atomic_store(&flags[(dir * 32 + jc) * 16], base + 1,
                       __ATOMIC_RELAXED, __HIP_MEMORY_SCOPE_AGENT);

  for (int t = 0; t < T_LEN; t++) {
    int t_eff = dir ? (T_LEN - 1 - t) : t;

    // gi prefetch (dense, vectorized; overlaps the poll)
    float gv[3][8];
#pragma unroll
    for (int g = 0; g < 3; g++) {
      const _Float16* gb = gi + ((size_t)dir * G3 + g * 512 + j) * MROWS + (size_t)t_eff * BATCH;
      union { uint2 u; _Float16 h[4]; } v0, v1;
      v0.u = *(const uint2*)(gb + q * 4);
      v1.u = *(const uint2*)(gb + 16 + q * 4);
#pragma unroll
      for (int r = 0; r < 4; r++) {
        gv[g][r]     = (float)v0.h[r];
        gv[g][4 + r] = (float)v1.h[r];
      }
    }

    // barrier: wait for all 32 producers of this dir
    {
      int target = base + t + 1;
      const int* fl = &flags[(dir * 32 + (lane & 31)) * 16];
      while (true) {
        int f = __hip_atomic_load(fl, __ATOMIC_RELAXED, __HIP_MEMORY_SCOPE_AGENT);
        if (__ballot(f >= target) == ~0ull) break;
        __builtin_amdgcn_s_sleep(1);
      }
      __builtin_amdgcn_fence(__ATOMIC_ACQUIRE, "workgroup");
    }

    // h(t): L3-direct atomic u64 loads -> A fragments
    const u32* hc = hbuf + ((size_t)(t & 1) * 2 + dir) * (BATCH * HSZ / 2);
    union { u64 q[2]; bf16x8 v; } a0[16], a1[16];
#pragma unroll
    for (int kg = 0; kg < 16; kg++) {
      const u32* p0 = hc + (size_t)l15 * (HSZ / 2) + kg * 16 + (kq >> 1);
      const u32* p1 = hc + (size_t)(16 + l15) * (HSZ / 2) + kg * 16 + (kq >> 1);
      a0[kg].q[0] = __hip_atomic_load((const u64*)p0,       __ATOMIC_RELAXED, __HIP_MEMORY_SCOPE_AGENT);
      a0[kg].q[1] = __hip_atomic_load((const u64*)(p0 + 2), __ATOMIC_RELAXED, __HIP_MEMORY_SCOPE_AGENT);
      a1[kg].q[0] = __hip_atomic_load((const u64*)p1,       __ATOMIC_RELAXED, __HIP_MEMORY_SCOPE_AGENT);
      a1[kg].q[1] = __hip_atomic_load((const u64*)(p1 + 2), __ATOMIC_RELAXED, __HIP_MEMORY_SCOPE_AGENT);
    }

    f32x4 aR0 = {}, aR1 = {}, aZ0 = {}, aZ1 = {}, aN0 = {}, aN1 = {};
#pragma unroll
    for (int kg = 0; kg < 16; kg++) {
      aR0 = __builtin_amdgcn_mfma_f32_16x16x32_bf16(a0[kg].v, wf[0][kg], aR0, 0, 0, 0);
      aR1 = __builtin_amdgcn_mfma_f32_16x16x32_bf16(a1[kg].v, wf[0][kg], aR1, 0, 0, 0);
      aZ0 = __builtin_amdgcn_mfma_f32_16x16x32_bf16(a0[kg].v, wf[1][kg], aZ0, 0, 0, 0);
      aZ1 = __builtin_amdgcn_mfma_f32_16x16x32_bf16(a1[kg].v, wf[1][kg], aZ1, 0, 0, 0);
      aN0 = __builtin_amdgcn_mfma_f32_16x16x32_bf16(a0[kg].v, wf[2][kg], aN0, 0, 0, 0);
      aN1 = __builtin_amdgcn_mfma_f32_16x16x32_bf16(a1[kg].v, wf[2][kg], aN1, 0, 0, 0);
    }

    // gates (v_rcp instead of precise divides; ~1ulp, well inside tolerance)
    float hv[8];
#pragma unroll
    for (int mt = 0; mt < 2; mt++)
#pragma unroll
      for (int r = 0; r < 4; r++) {
        int i = mt * 4 + r;
        float aR = mt ? aR1[r] : aR0[r];
        float aZ = mt ? aZ1[r] : aZ0[r];
        float aN = mt ? aN1[r] : aN0[r];
        float xr = gv[0][i] + aR + bhr;
        float xz = gv[1][i] + aZ + bhz;
        xr = fminf(fmaxf(xr, -40.f), 40.f);
        xz = fminf(fmaxf(xz, -40.f), 40.f);
        float rr = __builtin_amdgcn_rcpf(1.f + __expf(-xr));
        float zz = __builtin_amdgcn_rcpf(1.f + __expf(-xz));
        float xn = gv[2][i] + rr * (aN + bhn);
        xn = fminf(fmaxf(xn, -15.f), 15.f);
        float e2 = __expf(2.f * xn);
        float nn = (e2 - 1.f) * __builtin_amdgcn_rcpf(e2 + 1.f);
        hv[i] = (1.f - zz) * nn + zz * hm[i];
        hm[i] = hv[i];
      }

    // publish h(t+1): write-through atomics, then waitcnt, then flag
    u32* hn = hbuf + ((size_t)((t + 1) & 1) * 2 + dir) * (BATCH * HSZ / 2);
#pragma unroll
    for (int i = 0; i < 8; i++) {
      int b = (i >> 2) * 16 + q * 4 + (i & 3);
      float partner = __shfl_xor(hv[i], 1);
      if (!(l15 & 1))
        __hip_atomic_store(&hn[(size_t)b * (HSZ / 2) + (j >> 1)], pack_bf16(hv[i], partner),
                           __ATOMIC_RELAXED, __HIP_MEMORY_SCOPE_AGENT);
    }
    __builtin_amdgcn_fence(__ATOMIC_RELEASE, "workgroup");
    __builtin_amdgcn_s_waitcnt(0);
    if (lane == 0)
      __hip_atomic_store(&flags[(dir * 32 + jc) * 16], base + t + 2,
                         __ATOMIC_RELAXED, __HIP_MEMORY_SCOPE_AGENT);

    // out stores: off critical path; REGULAR stores (ack at L2, keep the
    // shared vmcnt counter clear for next step's poll)
#pragma unroll
    for (int i = 0; i < 8; i++) {
      int b = (i >> 2) * 16 + q * 4 + (i & 3);
      size_t oidx = ((size_t)t_eff * BATCH + b) * 1024 + dir * HSZ + j;
      if (outF) outF[oidx] = hv[i];
      if (outB) outB[oidx] = f2bf(hv[i]);
    }
  }
}

// ---------- launch ----------
extern "C" void kernel_launch(void* const* d_in, const int* in_sizes, int n_in,
                              void* d_out, int out_size, void* d_ws, size_t ws_size,
                              hipStream_t stream)
{
  const float* x  = (const float*)d_in[0];
  const float* h0 = (const float*)d_in[1];
  const float* w_ih[3] = {(const float*)d_in[2], (const float*)d_in[6], (const float*)d_in[10]};
  const float* w_hh[3] = {(const float*)d_in[3], (const float*)d_in[7], (const float*)d_in[11]};
  const float* b_ih[3] = {(const float*)d_in[4], (const float*)d_in[8], (const float*)d_in[12]};
  const float* b_hh[3] = {(const float*)d_in[5], (const float*)d_in[9], (const float*)d_in[13]};

  char* ws = (char*)d_ws;
  size_t off = 0;
  auto alloc = [&](size_t bytes) {
    void* p = ws + off;
    off = (off + bytes + 255) & ~(size_t)255;
    return p;
  };
  int* flags = (int*)alloc(4096);                                  // 64 x 64B lines
  u32* hbuf = (u32*)alloc((size_t)2 * 2 * BATCH * (HSZ / 2) * 4);  // packed bf16 ping-pong
  u16* xbf  = (u16*)alloc((size_t)16384 * 256 * 2);
  u16* lobf = (u16*)alloc((size_t)16384 * 1024 * 2);
  u16* wihT[3];
  wihT[0] = (u16*)alloc((size_t)2 * G3 * 256 * 2);
  wihT[1] = (u16*)alloc((size_t)2 * G3 * 1024 * 2);
  wihT[2] = (u16*)alloc((size_t)2 * G3 * 1024 * 2);
  u16* whhT[3];
  for (int l = 0; l < 3; l++) whhT[l] = (u16*)alloc((size_t)2 * G3 * 512 * 2);
  _Float16* gi = (_Float16*)alloc((size_t)2 * T_LEN * BATCH * G3 * 2);

  hipMemsetAsync(flags, 0, 4096, stream);

  convert_x<<<4096, 256, 0, stream>>>(x, xbf, 16384 * 256 / 4);
  transpose_bf16<<<dim3(48, 8, 2),  256, 0, stream>>>(w_ih[0], wihT[0], 256,  G3);
  transpose_bf16<<<dim3(48, 32, 2), 256, 0, stream>>>(w_ih[1], wihT[1], 1024, G3);
  transpose_bf16<<<dim3(48, 32, 2), 256, 0, stream>>>(w_ih[2], wihT[2], 1024, G3);
  for (int l = 0; l < 3; l++)
    transpose_bf16<<<dim3(48, 16, 2), 256, 0, stream>>>(w_hh[l], whhT[l], 512, G3);

  const int M = T_LEN * BATCH;
  for (int l = 0; l < 3; l++) {
    int K = (l == 0) ? 256 : 1024;
    const u16* Ain = (l == 0) ? xbf : lobf;
    gemm_gi<<<dim3(M / 128, G3 / 128, 2), 256, 0, stream>>>(Ain, wihT[l], b_ih[l], gi, M, K);
    float* oF = (l == 2) ? (float*)d_out : nullptr;
    u16* oB = (l < 2) ? lobf : nullptr;
    gru_rec<<<64, 64, 0, stream>>>(gi, whhT[l], b_hh[l],
                                   h0 + (size_t)l * 2 * BATCH * HSZ,
                                   oF, oB, hbuf, flags, l * 513);
  }
}

// Round 2
// 6821.497 us; speedup vs baseline: 1.3867x; 1.3867x over previous
//
#include <hip/hip_runtime.h>

#define T_LEN 512
#define BATCH 32
#define HSZ 512
#define G3 1536
#define MROWS 16384  // T_LEN * BATCH

typedef unsigned int u32;
typedef unsigned long long u64;
typedef unsigned short u16;
typedef __attribute__((ext_vector_type(8))) short bf16x8;
typedef __attribute__((ext_vector_type(4))) float f32x4;

// ---------- helpers ----------
static __device__ __forceinline__ u16 f2bf(float x) {
  u32 u = __float_as_uint(x);
  u32 r = (u + 0x7FFFu + ((u >> 16) & 1u)) >> 16;
  return (u16)r;
}
static __device__ __forceinline__ u32 pack_bf16(float a, float b) {
  return (u32)f2bf(a) | ((u32)f2bf(b) << 16);
}
static __device__ __forceinline__ float nz(float x) { return (x == x) ? x : 0.f; }

// ---------- conversion kernels ----------
__global__ __launch_bounds__(256) void transpose_bf16(
    const float* __restrict__ src, u16* __restrict__ dst, int K, int N)
{
  int dirz = blockIdx.z;
  src += (size_t)dirz * K * N;
  dst += (size_t)dirz * N * K;
  __shared__ float tile[32][33];
  int n0 = blockIdx.x * 32, k0 = blockIdx.y * 32;
  int tx = threadIdx.x & 31, ty = threadIdx.x >> 5;
#pragma unroll
  for (int i = ty; i < 32; i += 8)
    tile[i][tx] = src[(size_t)(k0 + i) * N + n0 + tx];
  __syncthreads();
#pragma unroll
  for (int i = ty; i < 32; i += 8)
    dst[(size_t)(n0 + i) * K + k0 + tx] = f2bf(tile[tx][i]);
}

__global__ __launch_bounds__(256) void convert_x(
    const float* __restrict__ src, u16* __restrict__ dst, int n4)
{
  int i = blockIdx.x * 256 + threadIdx.x;
  if (i >= n4) return;
  float4 v = ((const float4*)src)[i];
  union { u16 h[4]; uint2 u; } o;
  o.h[0] = f2bf(v.x); o.h[1] = f2bf(v.y); o.h[2] = f2bf(v.z); o.h[3] = f2bf(v.w);
  ((uint2*)dst)[i] = o.u;
}

// ---------- input-gate GEMM ----------
// C TRANSPOSED: [2][N=G3][M] fp16, so the recurrent kernel reads
// batch-contiguous 8B chunks.
__global__ __launch_bounds__(256) void gemm_gi(
    const u16* __restrict__ A,   // [M][K] bf16
    const u16* __restrict__ Bw,  // [2][N][K] bf16
    const float* __restrict__ bias,
    _Float16* __restrict__ C,    // [2][N][M]  (transposed!)
    int M, int K)
{
  const int N = G3;
  int dir = blockIdx.z;
  const u16* Bd = Bw + (size_t)dir * N * K;
  _Float16* Cd = C + (size_t)dir * N * M;
  const float* biasd = bias + dir * N;

  int tm = blockIdx.x * 128;
  int tn = blockIdx.y * 128;

  __shared__ u16 sA[128][40];
  __shared__ u16 sB[128][40];

  int tid = threadIdx.x;
  int lane = tid & 63, wave = tid >> 6;
  int wm = (wave & 1) << 6, wn = (wave >> 1) << 6;

  f32x4 acc[4][4] = {};

  int srow = tid >> 1, shalf = (tid & 1) << 4;
  const u16* pa = A + (size_t)(tm + srow) * K + shalf;
  const u16* pb = Bd + (size_t)(tn + srow) * K + shalf;

  for (int k0 = 0; k0 < K; k0 += 32) {
    uint4 va0 = *(const uint4*)(pa + k0);
    uint4 va1 = *(const uint4*)(pa + k0 + 8);
    uint4 vb0 = *(const uint4*)(pb + k0);
    uint4 vb1 = *(const uint4*)(pb + k0 + 8);
    *(uint4*)&sA[srow][shalf]     = va0;
    *(uint4*)&sA[srow][shalf + 8] = va1;
    *(uint4*)&sB[srow][shalf]     = vb0;
    *(uint4*)&sB[srow][shalf + 8] = vb1;
    __syncthreads();
    int kg = (lane >> 4) << 3;
    int r16 = lane & 15;
    bf16x8 af[4], bfr[4];
#pragma unroll
    for (int f = 0; f < 4; f++) {
      af[f]  = *(const bf16x8*)&sA[wm + f * 16 + r16][kg];
      bfr[f] = *(const bf16x8*)&sB[wn + f * 16 + r16][kg];
    }
#pragma unroll
    for (int fm = 0; fm < 4; fm++)
#pragma unroll
      for (int fn = 0; fn < 4; fn++)
        acc[fm][fn] = __builtin_amdgcn_mfma_f32_16x16x32_bf16(af[fm], bfr[fn], acc[fm][fn], 0, 0, 0);
    __syncthreads();
  }

  // epilogue: C^T store, 4 consecutive rows per lane -> one 8B store
  int col4 = lane & 15, rbase = (lane >> 4) << 2;
#pragma unroll
  for (int fn = 0; fn < 4; fn++) {
    int col = tn + wn + fn * 16 + col4;
    float bv = biasd[col];
#pragma unroll
    for (int fm = 0; fm < 4; fm++) {
      int row0 = tm + wm + fm * 16 + rbase;
      union { _Float16 h[4]; uint2 u; } o;
#pragma unroll
      for (int r = 0; r < 4; r++)
        o.h[r] = (_Float16)nz(acc[fm][fn][r] + bv);
      *(uint2*)&Cd[(size_t)col * M + row0] = o.u;
    }
  }
}

// ---------- persistent recurrent kernel ----------
// 64 blocks x 64 threads (1 wave). block=(dir,jc): 16 j-cols, 32 batches, 3 gates.
// R2: W_hh back in LDS (R1's "registers" plan exceeded the allocator's budget;
// it re-materialized the loads inside the step loop -> +660us). New LDS layout
// is MFMA-FRAGMENT-ORDERED: sWf[g][kg][lane][8] so the per-step ds_read_b128
// is lane-contiguous (base + lane*16B) = conflict-free, vs the old [j][k]
// layout's 8-lane bank-group aliasing (6.29M conflict cycles measured).
__global__ __launch_bounds__(64, 1) void gru_rec(
    const _Float16* __restrict__ gi,   // [2][G3][MROWS] fp16 (transposed)
    const u16* __restrict__ whhT,      // [2][G3][HSZ] bf16
    const float* __restrict__ bhh,     // [2][G3]
    const float* __restrict__ h0,      // [2][B][HSZ]
    float* __restrict__ outF,          // [T][B][1024] or null
    u16* __restrict__ outB,            // [T][B][1024] bf16 or null
    u32* __restrict__ hbuf,            // [2 buf][2 dir][B][HSZ/2] packed bf16
    int* __restrict__ flags,           // [2][32] x 64B-padded lines
    int base)                          // layer * 513
{
  int dir = blockIdx.x >> 5;
  int jc  = blockIdx.x & 31;
  int lane = threadIdx.x;          // one wave
  int l15 = lane & 15;
  int q   = lane >> 4;             // 0..3
  int j   = jc * 16 + l15;         // output column

  // fragment-ordered W_hh: sWf[(g*16+kg)*64 + lane][8 bf16]  (48 KB)
  __shared__ u16 sWf[3 * 16 * 64 * 8];

  // staging: LDS side linear (lane*16B), global side gathered.
  // element (g,kg,lane=(q,l15)) <- whhT[dir][g*512 + jc*16 + l15][kg*32 + q*8]
#pragma unroll
  for (int it = 0; it < 48; it++) {
    int g = it >> 4, kg = it & 15;
    const u16* src = whhT + ((size_t)dir * G3 + g * 512 + jc * 16 + l15) * HSZ + kg * 32 + q * 8;
    *(uint4*)&sWf[(it * 64 + lane) * 8] = *(const uint4*)src;
  }
  __syncthreads();

  float bhr = bhh[dir * G3 + j];
  float bhz = bhh[dir * G3 + 512 + j];
  float bhn = bhh[dir * G3 + 1024 + j];

  float hm[8];
#pragma unroll
  for (int mt = 0; mt < 2; mt++)
#pragma unroll
    for (int r = 0; r < 4; r++)
      hm[mt * 4 + r] = h0[((size_t)dir * BATCH + mt * 16 + q * 4 + r) * HSZ + j];

  // publish h0 into buffer 0 (write-through atomics, packed pairs)
  {
    u32* hb = hbuf + (size_t)dir * (BATCH * HSZ / 2);
#pragma unroll
    for (int i = 0; i < 8; i++) {
      int b = (i >> 2) * 16 + q * 4 + (i & 3);
      float partner = __shfl_xor(hm[i], 1);
      if (!(l15 & 1))
        __hip_atomic_store(&hb[(size_t)b * (HSZ / 2) + (j >> 1)], pack_bf16(hm[i], partner),
                           __ATOMIC_RELAXED, __HIP_MEMORY_SCOPE_AGENT);
    }
  }
  __builtin_amdgcn_fence(__ATOMIC_RELEASE, "workgroup");
  __builtin_amdgcn_s_waitcnt(0);
  if (lane == 0)
    __hip_atomic_store(&flags[(dir * 32 + jc) * 16], base + 1,
                       __ATOMIC_RELAXED, __HIP_MEMORY_SCOPE_AGENT);

  for (int t = 0; t < T_LEN; t++) {
    int t_eff = dir ? (T_LEN - 1 - t) : t;

    // gi prefetch (dense, vectorized; latency hides under the poll wait)
    float gv[3][8];
#pragma unroll
    for (int g = 0; g < 3; g++) {
      const _Float16* gb = gi + ((size_t)dir * G3 + g * 512 + j) * MROWS + (size_t)t_eff * BATCH;
      union { uint2 u; _Float16 h[4]; } v0, v1;
      v0.u = *(const uint2*)(gb + q * 4);
      v1.u = *(const uint2*)(gb + 16 + q * 4);
#pragma unroll
      for (int r = 0; r < 4; r++) {
        gv[g][r]     = (float)v0.h[r];
        gv[g][4 + r] = (float)v1.h[r];
      }
    }

    // barrier: wait for all 32 producers of this dir (no sleep: detect
    // cadence is the ~600cy flag-load latency anyway)
    {
      int target = base + t + 1;
      const int* fl = &flags[(dir * 32 + (lane & 31)) * 16];
      while (true) {
        int f = __hip_atomic_load(fl, __ATOMIC_RELAXED, __HIP_MEMORY_SCOPE_AGENT);
        if (__ballot(f >= target) == ~0ull) break;
      }
      __builtin_amdgcn_fence(__ATOMIC_ACQUIRE, "workgroup");
    }

    // h(t): L3-direct atomic u64 loads -> A fragments
    const u32* hc = hbuf + ((size_t)(t & 1) * 2 + dir) * (BATCH * HSZ / 2);
    union { u64 q[2]; bf16x8 v; } a0[16], a1[16];
    int kq = q * 8;
#pragma unroll
    for (int kg = 0; kg < 16; kg++) {
      const u32* p0 = hc + (size_t)l15 * (HSZ / 2) + kg * 16 + (kq >> 1);
      const u32* p1 = hc + (size_t)(16 + l15) * (HSZ / 2) + kg * 16 + (kq >> 1);
      a0[kg].q[0] = __hip_atomic_load((const u64*)p0,       __ATOMIC_RELAXED, __HIP_MEMORY_SCOPE_AGENT);
      a0[kg].q[1] = __hip_atomic_load((const u64*)(p0 + 2), __ATOMIC_RELAXED, __HIP_MEMORY_SCOPE_AGENT);
      a1[kg].q[0] = __hip_atomic_load((const u64*)p1,       __ATOMIC_RELAXED, __HIP_MEMORY_SCOPE_AGENT);
      a1[kg].q[1] = __hip_atomic_load((const u64*)(p1 + 2), __ATOMIC_RELAXED, __HIP_MEMORY_SCOPE_AGENT);
    }

    f32x4 aR0 = {}, aR1 = {}, aZ0 = {}, aZ1 = {}, aN0 = {}, aN1 = {};
#pragma unroll
    for (int kg = 0; kg < 16; kg++) {
      bf16x8 wR = *(const bf16x8*)&sWf[((0 * 16 + kg) * 64 + lane) * 8];
      bf16x8 wZ = *(const bf16x8*)&sWf[((1 * 16 + kg) * 64 + lane) * 8];
      bf16x8 wN = *(const bf16x8*)&sWf[((2 * 16 + kg) * 64 + lane) * 8];
      aR0 = __builtin_amdgcn_mfma_f32_16x16x32_bf16(a0[kg].v, wR, aR0, 0, 0, 0);
      aR1 = __builtin_amdgcn_mfma_f32_16x16x32_bf16(a1[kg].v, wR, aR1, 0, 0, 0);
      aZ0 = __builtin_amdgcn_mfma_f32_16x16x32_bf16(a0[kg].v, wZ, aZ0, 0, 0, 0);
      aZ1 = __builtin_amdgcn_mfma_f32_16x16x32_bf16(a1[kg].v, wZ, aZ1, 0, 0, 0);
      aN0 = __builtin_amdgcn_mfma_f32_16x16x32_bf16(a0[kg].v, wN, aN0, 0, 0, 0);
      aN1 = __builtin_amdgcn_mfma_f32_16x16x32_bf16(a1[kg].v, wN, aN1, 0, 0, 0);
    }

    // gates (rcp ~1ulp, inside tolerance)
    float hv[8];
#pragma unroll
    for (int mt = 0; mt < 2; mt++)
#pragma unroll
      for (int r = 0; r < 4; r++) {
        int i = mt * 4 + r;
        float aR = mt ? aR1[r] : aR0[r];
        float aZ = mt ? aZ1[r] : aZ0[r];
        float aN = mt ? aN1[r] : aN0[r];
        float xr = gv[0][i] + aR + bhr;
        float xz = gv[1][i] + aZ + bhz;
        xr = fminf(fmaxf(xr, -40.f), 40.f);
        xz = fminf(fmaxf(xz, -40.f), 40.f);
        float rr = __builtin_amdgcn_rcpf(1.f + __expf(-xr));
        float zz = __builtin_amdgcn_rcpf(1.f + __expf(-xz));
        float xn = gv[2][i] + rr * (aN + bhn);
        xn = fminf(fmaxf(xn, -15.f), 15.f);
        float e2 = __expf(2.f * xn);
        float nn = (e2 - 1.f) * __builtin_amdgcn_rcpf(e2 + 1.f);
        hv[i] = (1.f - zz) * nn + zz * hm[i];
        hm[i] = hv[i];
      }

    // publish h(t+1): write-through atomics, then waitcnt, then flag
    u32* hn = hbuf + ((size_t)((t + 1) & 1) * 2 + dir) * (BATCH * HSZ / 2);
#pragma unroll
    for (int i = 0; i < 8; i++) {
      int b = (i >> 2) * 16 + q * 4 + (i & 3);
      float partner = __shfl_xor(hv[i], 1);
      if (!(l15 & 1))
        __hip_atomic_store(&hn[(size_t)b * (HSZ / 2) + (j >> 1)], pack_bf16(hv[i], partner),
                           __ATOMIC_RELAXED, __HIP_MEMORY_SCOPE_AGENT);
    }
    __builtin_amdgcn_fence(__ATOMIC_RELEASE, "workgroup");
    __builtin_amdgcn_s_waitcnt(0);
    if (lane == 0)
      __hip_atomic_store(&flags[(dir * 32 + jc) * 16], base + t + 2,
                         __ATOMIC_RELAXED, __HIP_MEMORY_SCOPE_AGENT);

    // out stores: off critical path; regular stores (ack at L2)
#pragma unroll
    for (int i = 0; i < 8; i++) {
      int b = (i >> 2) * 16 + q * 4 + (i & 3);
      size_t oidx = ((size_t)t_eff * BATCH + b) * 1024 + dir * HSZ + j;
      if (outF) outF[oidx] = hv[i];
      if (outB) outB[oidx] = f2bf(hv[i]);
    }
  }
}

// ---------- launch ----------
extern "C" void kernel_launch(void* const* d_in, const int* in_sizes, int n_in,
                              void* d_out, int out_size, void* d_ws, size_t ws_size,
                              hipStream_t stream)
{
  const float* x  = (const float*)d_in[0];
  const float* h0 = (const float*)d_in[1];
  const float* w_ih[3] = {(const float*)d_in[2], (const float*)d_in[6], (const float*)d_in[10]};
  const float* w_hh[3] = {(const float*)d_in[3], (const float*)d_in[7], (const float*)d_in[11]};
  const float* b_ih[3] = {(const float*)d_in[4], (const float*)d_in[8], (const float*)d_in[12]};
  const float* b_hh[3] = {(const float*)d_in[5], (const float*)d_in[9], (const float*)d_in[13]};

  char* ws = (char*)d_ws;
  size_t off = 0;
  auto alloc = [&](size_t bytes) {
    void* p = ws + off;
    off = (off + bytes + 255) & ~(size_t)255;
    return p;
  };
  int* flags = (int*)alloc(4096);                                  // 64 x 64B lines
  u32* hbuf = (u32*)alloc((size_t)2 * 2 * BATCH * (HSZ / 2) * 4);  // packed bf16 ping-pong
  u16* xbf  = (u16*)alloc((size_t)16384 * 256 * 2);
  u16* lobf = (u16*)alloc((size_t)16384 * 1024 * 2);
  u16* wihT[3];
  wihT[0] = (u16*)alloc((size_t)2 * G3 * 256 * 2);
  wihT[1] = (u16*)alloc((size_t)2 * G3 * 1024 * 2);
  wihT[2] = (u16*)alloc((size_t)2 * G3 * 1024 * 2);
  u16* whhT[3];
  for (int l = 0; l < 3; l++) whhT[l] = (u16*)alloc((size_t)2 * G3 * 512 * 2);
  _Float16* gi = (_Float16*)alloc((size_t)2 * T_LEN * BATCH * G3 * 2);

  hipMemsetAsync(flags, 0, 4096, stream);

  convert_x<<<4096, 256, 0, stream>>>(x, xbf, 16384 * 256 / 4);
  transpose_bf16<<<dim3(48, 8, 2),  256, 0, stream>>>(w_ih[0], wihT[0], 256,  G3);
  transpose_bf16<<<dim3(48, 32, 2), 256, 0, stream>>>(w_ih[1], wihT[1], 1024, G3);
  transpose_bf16<<<dim3(48, 32, 2), 256, 0, stream>>>(w_ih[2], wihT[2], 1024, G3);
  for (int l = 0; l < 3; l++)
    transpose_bf16<<<dim3(48, 16, 2), 256, 0, stream>>>(w_hh[l], whhT[l], 512, G3);

  const int M = T_LEN * BATCH;
  for (int l = 0; l < 3; l++) {
    int K = (l == 0) ? 256 : 1024;
    const u16* Ain = (l == 0) ? xbf : lobf;
    gemm_gi<<<dim3(M / 128, G3 / 128, 2), 256, 0, stream>>>(Ain, wihT[l], b_ih[l], gi, M, K);
    float* oF = (l == 2) ? (float*)d_out : nullptr;
    u16* oB = (l < 2) ? lobf : nullptr;
    gru_rec<<<64, 64, 0, stream>>>(gi, whhT[l], b_hh[l],
                                   h0 + (size_t)l * 2 * BATCH * HSZ,
                                   oF, oB, hbuf, flags, l * 513);
  }
}

// Round 3
// 6697.243 us; speedup vs baseline: 1.4124x; 1.0186x over previous
//
#include <hip/hip_runtime.h>

#define T_LEN 512
#define BATCH 32
#define HSZ 512
#define G3 1536
#define MROWS 16384  // T_LEN * BATCH

typedef unsigned int u32;
typedef unsigned long long u64;
typedef unsigned short u16;
typedef __attribute__((ext_vector_type(8))) short bf16x8;
typedef __attribute__((ext_vector_type(4))) float f32x4;

// ---------- helpers ----------
static __device__ __forceinline__ u16 f2bf(float x) {
  u32 u = __float_as_uint(x);
  u32 r = (u + 0x7FFFu + ((u >> 16) & 1u)) >> 16;
  return (u16)r;
}
static __device__ __forceinline__ u32 pack_bf16(float a, float b) {
  return (u32)f2bf(a) | ((u32)f2bf(b) << 16);
}
static __device__ __forceinline__ float nz(float x) { return (x == x) ? x : 0.f; }

// ---------- conversion kernels ----------
__global__ __launch_bounds__(256) void transpose_bf16(
    const float* __restrict__ src, u16* __restrict__ dst, int K, int N)
{
  int dirz = blockIdx.z;
  src += (size_t)dirz * K * N;
  dst += (size_t)dirz * N * K;
  __shared__ float tile[32][33];
  int n0 = blockIdx.x * 32, k0 = blockIdx.y * 32;
  int tx = threadIdx.x & 31, ty = threadIdx.x >> 5;
#pragma unroll
  for (int i = ty; i < 32; i += 8)
    tile[i][tx] = src[(size_t)(k0 + i) * N + n0 + tx];
  __syncthreads();
#pragma unroll
  for (int i = ty; i < 32; i += 8)
    dst[(size_t)(n0 + i) * K + k0 + tx] = f2bf(tile[tx][i]);
}

__global__ __launch_bounds__(256) void convert_x(
    const float* __restrict__ src, u16* __restrict__ dst, int n4)
{
  int i = blockIdx.x * 256 + threadIdx.x;
  if (i >= n4) return;
  float4 v = ((const float4*)src)[i];
  union { u16 h[4]; uint2 u; } o;
  o.h[0] = f2bf(v.x); o.h[1] = f2bf(v.y); o.h[2] = f2bf(v.z); o.h[3] = f2bf(v.w);
  ((uint2*)dst)[i] = o.u;
}

// ---------- input-gate GEMM ----------
// C TRANSPOSED: [2][N=G3][M] fp16, so the recurrent kernel reads
// batch-contiguous 8B chunks.
__global__ __launch_bounds__(256) void gemm_gi(
    const u16* __restrict__ A,   // [M][K] bf16
    const u16* __restrict__ Bw,  // [2][N][K] bf16
    const float* __restrict__ bias,
    _Float16* __restrict__ C,    // [2][N][M]  (transposed!)
    int M, int K)
{
  const int N = G3;
  int dir = blockIdx.z;
  const u16* Bd = Bw + (size_t)dir * N * K;
  _Float16* Cd = C + (size_t)dir * N * M;
  const float* biasd = bias + dir * N;

  int tm = blockIdx.x * 128;
  int tn = blockIdx.y * 128;

  __shared__ u16 sA[128][40];
  __shared__ u16 sB[128][40];

  int tid = threadIdx.x;
  int lane = tid & 63, wave = tid >> 6;
  int wm = (wave & 1) << 6, wn = (wave >> 1) << 6;

  f32x4 acc[4][4] = {};

  int srow = tid >> 1, shalf = (tid & 1) << 4;
  const u16* pa = A + (size_t)(tm + srow) * K + shalf;
  const u16* pb = Bd + (size_t)(tn + srow) * K + shalf;

  for (int k0 = 0; k0 < K; k0 += 32) {
    uint4 va0 = *(const uint4*)(pa + k0);
    uint4 va1 = *(const uint4*)(pa + k0 + 8);
    uint4 vb0 = *(const uint4*)(pb + k0);
    uint4 vb1 = *(const uint4*)(pb + k0 + 8);
    *(uint4*)&sA[srow][shalf]     = va0;
    *(uint4*)&sA[srow][shalf + 8] = va1;
    *(uint4*)&sB[srow][shalf]     = vb0;
    *(uint4*)&sB[srow][shalf + 8] = vb1;
    __syncthreads();
    int kg = (lane >> 4) << 3;
    int r16 = lane & 15;
    bf16x8 af[4], bfr[4];
#pragma unroll
    for (int f = 0; f < 4; f++) {
      af[f]  = *(const bf16x8*)&sA[wm + f * 16 + r16][kg];
      bfr[f] = *(const bf16x8*)&sB[wn + f * 16 + r16][kg];
    }
#pragma unroll
    for (int fm = 0; fm < 4; fm++)
#pragma unroll
      for (int fn = 0; fn < 4; fn++)
        acc[fm][fn] = __builtin_amdgcn_mfma_f32_16x16x32_bf16(af[fm], bfr[fn], acc[fm][fn], 0, 0, 0);
    __syncthreads();
  }

  // epilogue: C^T store, 4 consecutive rows per lane -> one 8B store
  int col4 = lane & 15, rbase = (lane >> 4) << 2;
#pragma unroll
  for (int fn = 0; fn < 4; fn++) {
    int col = tn + wn + fn * 16 + col4;
    float bv = biasd[col];
#pragma unroll
    for (int fm = 0; fm < 4; fm++) {
      int row0 = tm + wm + fm * 16 + rbase;
      union { _Float16 h[4]; uint2 u; } o;
#pragma unroll
      for (int r = 0; r < 4; r++)
        o.h[r] = (_Float16)nz(acc[fm][fn][r] + bv);
      *(uint2*)&Cd[(size_t)col * M + row0] = o.u;
    }
  }
}

// ---------- persistent recurrent kernel ----------
// 64 blocks x 64 threads (1 wave). block=(dir,jc): 16 j-cols, 32 batches, 3 gates.
// R3: break vmcnt FIFO coupling on the step critical path:
//  * gi loads software-pipelined one step ahead (raw fp16 in 12 VGPRs,
//    issued AFTER the flag store -> fully covered by publish-ack + detect)
//  * flag poll via flat_load + lgkmcnt(0): flat ops count in BOTH counters,
//    so the poll ignores the vmcnt backlog (gi / out stores) entirely
//  * acquire fence dropped: asm "memory" clobber gives compiler ordering;
//    HW ordering holds (sc1 loads sample L3 after the flag's L3 sample)
__global__ __launch_bounds__(64, 1) void gru_rec(
    const _Float16* __restrict__ gi,   // [2][G3][MROWS] fp16 (transposed)
    const u16* __restrict__ whhT,      // [2][G3][HSZ] bf16
    const float* __restrict__ bhh,     // [2][G3]
    const float* __restrict__ h0,      // [2][B][HSZ]
    float* __restrict__ outF,          // [T][B][1024] or null
    u16* __restrict__ outB,            // [T][B][1024] bf16 or null
    u32* __restrict__ hbuf,            // [2 buf][2 dir][B][HSZ/2] packed bf16
    int* __restrict__ flags,           // [2][32] x 64B-padded lines
    int base)                          // layer * 513
{
  int dir = blockIdx.x >> 5;
  int jc  = blockIdx.x & 31;
  int lane = threadIdx.x;          // one wave
  int l15 = lane & 15;
  int q   = lane >> 4;             // 0..3
  int j   = jc * 16 + l15;         // output column

  // fragment-ordered W_hh: sWf[(g*16+kg)*64 + lane][8 bf16]  (48 KB)
  __shared__ u16 sWf[3 * 16 * 64 * 8];

#pragma unroll
  for (int it = 0; it < 48; it++) {
    int g = it >> 4, kg = it & 15;
    const u16* src = whhT + ((size_t)dir * G3 + g * 512 + jc * 16 + l15) * HSZ + kg * 32 + q * 8;
    *(uint4*)&sWf[(it * 64 + lane) * 8] = *(const uint4*)src;
  }
  __syncthreads();

  float bhr = bhh[dir * G3 + j];
  float bhz = bhh[dir * G3 + 512 + j];
  float bhn = bhh[dir * G3 + 1024 + j];

  float hm[8];
#pragma unroll
  for (int mt = 0; mt < 2; mt++)
#pragma unroll
    for (int r = 0; r < 4; r++)
      hm[mt * 4 + r] = h0[((size_t)dir * BATCH + mt * 16 + q * 4 + r) * HSZ + j];

  // publish h0 into buffer 0 (write-through atomics, packed pairs)
  {
    u32* hb = hbuf + (size_t)dir * (BATCH * HSZ / 2);
#pragma unroll
    for (int i = 0; i < 8; i++) {
      int b = (i >> 2) * 16 + q * 4 + (i & 3);
      float partner = __shfl_xor(hm[i], 1);
      if (!(l15 & 1))
        __hip_atomic_store(&hb[(size_t)b * (HSZ / 2) + (j >> 1)], pack_bf16(hm[i], partner),
                           __ATOMIC_RELAXED, __HIP_MEMORY_SCOPE_AGENT);
    }
  }
  __builtin_amdgcn_fence(__ATOMIC_RELEASE, "workgroup");
  __builtin_amdgcn_s_waitcnt(0);
  if (lane == 0)
    __hip_atomic_store(&flags[(dir * 32 + jc) * 16], base + 1,
                       __ATOMIC_RELAXED, __HIP_MEMORY_SCOPE_AGENT);
  __builtin_amdgcn_sched_barrier(0);

  // gi(0) prefetch (raw fp16 pairs; converted at use)
  uint2 gir[2][3][2];
  {
    int te0 = dir ? (T_LEN - 1) : 0;
#pragma unroll
    for (int g = 0; g < 3; g++) {
      const _Float16* gb = gi + ((size_t)dir * G3 + g * 512 + j) * MROWS + (size_t)te0 * BATCH;
      gir[0][g][0] = *(const uint2*)(gb + q * 4);
      gir[0][g][1] = *(const uint2*)(gb + 16 + q * 4);
    }
  }

  for (int t2 = 0; t2 < T_LEN; t2 += 2) {
#pragma unroll
    for (int p = 0; p < 2; p++) {
      const int t = t2 + p;
      const int t_eff = dir ? (T_LEN - 1 - t) : t;

      // 1. detect: flat poll, waits lgkmcnt only (ignores vmcnt backlog)
      {
        const int target = base + t + 1;
        const int* fl = &flags[(dir * 32 + (lane & 31)) * 16];
        while (true) {
          int f;
          asm volatile("flat_load_dword %0, %1 sc0 sc1\n\t"
                       "s_waitcnt lgkmcnt(0)"
                       : "=&v"(f) : "v"(fl) : "memory");
          __builtin_amdgcn_sched_barrier(0);
          if (__ballot(f >= target) == ~0ull) break;
        }
      }

      // 2. h(t): L3-direct atomic u64 loads -> A fragments
      const u32* hc = hbuf + ((size_t)(t & 1) * 2 + dir) * (BATCH * HSZ / 2);
      union { u64 q[2]; bf16x8 v; } a0[16], a1[16];
#pragma unroll
      for (int kg = 0; kg < 16; kg++) {
        const u32* p0 = hc + (size_t)l15 * (HSZ / 2) + kg * 16 + q * 4;
        const u32* p1 = hc + (size_t)(16 + l15) * (HSZ / 2) + kg * 16 + q * 4;
        a0[kg].q[0] = __hip_atomic_load((const u64*)p0,       __ATOMIC_RELAXED, __HIP_MEMORY_SCOPE_AGENT);
        a0[kg].q[1] = __hip_atomic_load((const u64*)(p0 + 2), __ATOMIC_RELAXED, __HIP_MEMORY_SCOPE_AGENT);
        a1[kg].q[0] = __hip_atomic_load((const u64*)p1,       __ATOMIC_RELAXED, __HIP_MEMORY_SCOPE_AGENT);
        a1[kg].q[1] = __hip_atomic_load((const u64*)(p1 + 2), __ATOMIC_RELAXED, __HIP_MEMORY_SCOPE_AGENT);
      }

      // 3. MFMA
      f32x4 aR0 = {}, aR1 = {}, aZ0 = {}, aZ1 = {}, aN0 = {}, aN1 = {};
#pragma unroll
      for (int kg = 0; kg < 16; kg++) {
        bf16x8 wR = *(const bf16x8*)&sWf[((0 * 16 + kg) * 64 + lane) * 8];
        bf16x8 wZ = *(const bf16x8*)&sWf[((1 * 16 + kg) * 64 + lane) * 8];
        bf16x8 wN = *(const bf16x8*)&sWf[((2 * 16 + kg) * 64 + lane) * 8];
        aR0 = __builtin_amdgcn_mfma_f32_16x16x32_bf16(a0[kg].v, wR, aR0, 0, 0, 0);
        aR1 = __builtin_amdgcn_mfma_f32_16x16x32_bf16(a1[kg].v, wR, aR1, 0, 0, 0);
        aZ0 = __builtin_amdgcn_mfma_f32_16x16x32_bf16(a0[kg].v, wZ, aZ0, 0, 0, 0);
        aZ1 = __builtin_amdgcn_mfma_f32_16x16x32_bf16(a1[kg].v, wZ, aZ1, 0, 0, 0);
        aN0 = __builtin_amdgcn_mfma_f32_16x16x32_bf16(a0[kg].v, wN, aN0, 0, 0, 0);
        aN1 = __builtin_amdgcn_mfma_f32_16x16x32_bf16(a1[kg].v, wN, aN1, 0, 0, 0);
      }

      // 4. gates (gi converted from raw fp16 here; rcp ~1ulp)
      float hv[8];
#pragma unroll
      for (int mt = 0; mt < 2; mt++)
#pragma unroll
        for (int r = 0; r < 4; r++) {
          int i = mt * 4 + r;
          union { uint2 u; _Float16 h[4]; } cr, cz, cn;
          cr.u = gir[p][0][mt]; cz.u = gir[p][1][mt]; cn.u = gir[p][2][mt];
          float aR = mt ? aR1[r] : aR0[r];
          float aZ = mt ? aZ1[r] : aZ0[r];
          float aN = mt ? aN1[r] : aN0[r];
          float xr = (float)cr.h[r] + aR + bhr;
          float xz = (float)cz.h[r] + aZ + bhz;
          xr = fminf(fmaxf(xr, -40.f), 40.f);
          xz = fminf(fmaxf(xz, -40.f), 40.f);
          float rr = __builtin_amdgcn_rcpf(1.f + __expf(-xr));
          float zz = __builtin_amdgcn_rcpf(1.f + __expf(-xz));
          float xn = (float)cn.h[r] + rr * (aN + bhn);
          xn = fminf(fmaxf(xn, -15.f), 15.f);
          float e2 = __expf(2.f * xn);
          float nn = (e2 - 1.f) * __builtin_amdgcn_rcpf(e2 + 1.f);
          hv[i] = (1.f - zz) * nn + zz * hm[i];
          hm[i] = hv[i];
        }

      // 5. publish h(t+1): write-through atomics, ack, flag
      u32* hn = hbuf + ((size_t)((t + 1) & 1) * 2 + dir) * (BATCH * HSZ / 2);
#pragma unroll
      for (int i = 0; i < 8; i++) {
        int b = (i >> 2) * 16 + q * 4 + (i & 3);
        float partner = __shfl_xor(hv[i], 1);
        if (!(l15 & 1))
          __hip_atomic_store(&hn[(size_t)b * (HSZ / 2) + (j >> 1)], pack_bf16(hv[i], partner),
                             __ATOMIC_RELAXED, __HIP_MEMORY_SCOPE_AGENT);
      }
      __builtin_amdgcn_fence(__ATOMIC_RELEASE, "workgroup");
      __builtin_amdgcn_s_waitcnt(0);
      if (lane == 0)
        __hip_atomic_store(&flags[(dir * 32 + jc) * 16], base + t + 2,
                           __ATOMIC_RELAXED, __HIP_MEMORY_SCOPE_AGENT);
      __builtin_amdgcn_sched_barrier(0);   // keep gin loads BELOW the ack+flag

      // 6. gi(t+1) prefetch into the other parity slot
      if (t + 1 < T_LEN) {
        int te1 = dir ? (T_LEN - 2 - t) : t + 1;
#pragma unroll
        for (int g = 0; g < 3; g++) {
          const _Float16* gb = gi + ((size_t)dir * G3 + g * 512 + j) * MROWS + (size_t)te1 * BATCH;
          gir[p ^ 1][g][0] = *(const uint2*)(gb + q * 4);
          gir[p ^ 1][g][1] = *(const uint2*)(gb + 16 + q * 4);
        }
      }

      // 7. out stores: off critical path (drained at next publish ack)
#pragma unroll
      for (int i = 0; i < 8; i++) {
        int b = (i >> 2) * 16 + q * 4 + (i & 3);
        size_t oidx = ((size_t)t_eff * BATCH + b) * 1024 + dir * HSZ + j;
        if (outF) outF[oidx] = hv[i];
        if (outB) outB[oidx] = f2bf(hv[i]);
      }
    }
  }
}

// ---------- launch ----------
extern "C" void kernel_launch(void* const* d_in, const int* in_sizes, int n_in,
                              void* d_out, int out_size, void* d_ws, size_t ws_size,
                              hipStream_t stream)
{
  const float* x  = (const float*)d_in[0];
  const float* h0 = (const float*)d_in[1];
  const float* w_ih[3] = {(const float*)d_in[2], (const float*)d_in[6], (const float*)d_in[10]};
  const float* w_hh[3] = {(const float*)d_in[3], (const float*)d_in[7], (const float*)d_in[11]};
  const float* b_ih[3] = {(const float*)d_in[4], (const float*)d_in[8], (const float*)d_in[12]};
  const float* b_hh[3] = {(const float*)d_in[5], (const float*)d_in[9], (const float*)d_in[13]};

  char* ws = (char*)d_ws;
  size_t off = 0;
  auto alloc = [&](size_t bytes) {
    void* p = ws + off;
    off = (off + bytes + 255) & ~(size_t)255;
    return p;
  };
  int* flags = (int*)alloc(4096);                                  // 64 x 64B lines
  u32* hbuf = (u32*)alloc((size_t)2 * 2 * BATCH * (HSZ / 2) * 4);  // packed bf16 ping-pong
  u16* xbf  = (u16*)alloc((size_t)16384 * 256 * 2);
  u16* lobf = (u16*)alloc((size_t)16384 * 1024 * 2);
  u16* wihT[3];
  wihT[0] = (u16*)alloc((size_t)2 * G3 * 256 * 2);
  wihT[1] = (u16*)alloc((size_t)2 * G3 * 1024 * 2);
  wihT[2] = (u16*)alloc((size_t)2 * G3 * 1024 * 2);
  u16* whhT[3];
  for (int l = 0; l < 3; l++) whhT[l] = (u16*)alloc((size_t)2 * G3 * 512 * 2);
  _Float16* gi = (_Float16*)alloc((size_t)2 * T_LEN * BATCH * G3 * 2);

  hipMemsetAsync(flags, 0, 4096, stream);

  convert_x<<<4096, 256, 0, stream>>>(x, xbf, 16384 * 256 / 4);
  transpose_bf16<<<dim3(48, 8, 2),  256, 0, stream>>>(w_ih[0], wihT[0], 256,  G3);
  transpose_bf16<<<dim3(48, 32, 2), 256, 0, stream>>>(w_ih[1], wihT[1], 1024, G3);
  transpose_bf16<<<dim3(48, 32, 2), 256, 0, stream>>>(w_ih[2], wihT[2], 1024, G3);
  for (int l = 0; l < 3; l++)
    transpose_bf16<<<dim3(48, 16, 2), 256, 0, stream>>>(w_hh[l], whhT[l], 512, G3);

  const int M = T_LEN * BATCH;
  for (int l = 0; l < 3; l++) {
    int K = (l == 0) ? 256 : 1024;
    const u16* Ain = (l == 0) ? xbf : lobf;
    gemm_gi<<<dim3(M / 128, G3 / 128, 2), 256, 0, stream>>>(Ain, wihT[l], b_ih[l], gi, M, K);
    float* oF = (l == 2) ? (float*)d_out : nullptr;
    u16* oB = (l < 2) ? lobf : nullptr;
    gru_rec<<<64, 64, 0, stream>>>(gi, whhT[l], b_hh[l],
                                   h0 + (size_t)l * 2 * BATCH * HSZ,
                                   oF, oB, hbuf, flags, l * 513);
  }
}